// Round 7
// baseline (190.967 us; speedup 1.0000x reference)
//
#include <hip/hip_runtime.h>

#define T_STEPS 512
#define CHUNK   32
#define NCHUNK  (T_STEPS / CHUNK)   // 16
#define EPB     32                  // elements per 512-thread block (16 lanes/elem)
#define ROWF    132                 // padded row: 33 float4
#define BUFF    (EPB * ROWF)        // 4224 floats per buffer
#define LOG2E   1.4426950408889634f

typedef float v2f __attribute__((ext_vector_type(2)));
typedef float v4f __attribute__((ext_vector_type(4)));

// Packed fp32 ops with op_sel broadcasts (numerics verified R2/R4):
// _lo: both result halves read src1.LOW  (op_sel_hi:[1,0,1])
// _hi: both result halves read src1.HIGH (op_sel:[0,1,0] op_sel_hi:[1,1,1])
__device__ __forceinline__ v2f pk_fma_lo(v2f w, v2f s, v2f c) {
    v2f d;
    asm("v_pk_fma_f32 %0, %1, %2, %3 op_sel_hi:[1,0,1]"
        : "=v"(d) : "v"(w), "v"(s), "v"(c));
    return d;
}
__device__ __forceinline__ void pk_fma_lo_acc(v2f& a, v2f w, v2f s) {
    asm("v_pk_fma_f32 %0, %1, %2, %0 op_sel_hi:[1,0,1]"
        : "+v"(a) : "v"(w), "v"(s));
}
__device__ __forceinline__ void pk_fma_hi_acc(v2f& a, v2f w, v2f s) {
    asm("v_pk_fma_f32 %0, %1, %2, %0 op_sel:[0,1,0] op_sel_hi:[1,1,1]"
        : "+v"(a) : "v"(w), "v"(s));
}
__device__ __forceinline__ v2f pk_mul_hi(v2f w, v2f s) {
    v2f d;
    asm("v_pk_mul_f32 %0, %1, %2 op_sel:[0,1] op_sel_hi:[1,1]"
        : "=v"(d) : "v"(w), "v"(s));
    return d;
}
__device__ __forceinline__ v2f pk_add2(v2f a, v2f b) {
    v2f d;
    asm("v_pk_add_f32 %0, %1, %2" : "=v"(d) : "v"(a), "v"(b));
    return d;
}

// DPP cross-lane: xor1=0xB1, xor2=0x4E, xor3=0x1B (quad_perm);
// xor7(within 8)=row_half_mirror 0x141; xor15(within 16)=row_mirror 0x140;
// xor8 = 0x140 o 0x141 (elements are 16-lane aligned).
template <int CTRL>
__device__ __forceinline__ float dppf(float v) {
    return __int_as_float(__builtin_amdgcn_update_dpp(
        0, __float_as_int(v), CTRL, 0xF, 0xF, true));
}

// 16 lanes/elem -> 2048 waves -> 2 waves/SIMD (the latency-hiding R4 proved
// we need: at 1 wave/SIMD the 4-trans serial chain leaves ~160 cyc/step of
// unfillable stall). Per lane: ONE pair-chain for its two gate rows
// (half0: (i_j,f_j), half1: (g_j,o_j)) via the R2 lo/hi op_sel broadcast —
// per-lane issue genuinely halves vs R0 (R1's mistake: 2 chains/row).
// Gate exp2 computed SIMT-wide (2/lane cover all 4 gates), exchanged across
// halves via composed-xor8 DPP; cell chain replicated in both halves
// (bitwise identical by commutativity — R1-verified). exp2 scales pre-folded
// into weights; cell pre-scaled ct=-2log2e*c; f-rcp folded into i*g rcp;
// x-projection pipelined one step ahead (R3).
// R6: amdgpu_waves_per_eu(2,2) — the only never-run-on-silicon ingredient
// of the twice-failed R5 build — replaced by the proven spelling
// __launch_bounds__(512, 2). Residency is non-critical (R4: 132 vs 52
// VGPR identical time), so losing the max-waves clamp costs nothing.
__global__ __launch_bounds__(512, 2)
void lstm_kernel(
    const float* __restrict__ x, const float* __restrict__ W_ih,
    const float* __restrict__ W_hh, const float* __restrict__ b_ih,
    const float* __restrict__ b_hh, const float* __restrict__ W_fc,
    const float* __restrict__ b_fc, float* __restrict__ out, int B)
{
    __shared__ float ldsx[2 * BUFF];

    const int tid = threadIdx.x;
    const int e   = tid >> 4;          // block-local element [0,32)
    const int L   = tid & 15;          // lane within element
    const int j   = L & 7;             // hidden unit
    const bool hGO = (L & 8) != 0;     // false: (i,f) rows; true: (g,o) rows

    const float nL  = -LOG2E;          // scale for i,f,o rows
    const float n2L = -2.0f * LOG2E;   // scale for g row
    const float P2L =  2.0f * LOG2E;

    // ---- this lane's two gate rows, packed (r0,r1); scales pre-folded ----
    const int r0 = hGO ? 16 + j : j;        // g : i
    const int r1 = hGO ? 24 + j : 8 + j;    // o : f
    const float sA = hGO ? n2L : nL;        // r0 scale (g gets -2log2e)

    v2f wx0 = v2f{sA * W_ih[r0 * 4 + 0], nL * W_ih[r1 * 4 + 0]};
    v2f wx1 = v2f{sA * W_ih[r0 * 4 + 1], nL * W_ih[r1 * 4 + 1]};
    v2f wx2 = v2f{sA * W_ih[r0 * 4 + 2], nL * W_ih[r1 * 4 + 2]};
    v2f wx3 = v2f{sA * W_ih[r0 * 4 + 3], nL * W_ih[r1 * 4 + 3]};

    // chain A consumes {h(j^0), s3(j^3), s4(j^4), s6(j^6)},
    // chain B consumes {s1(j^1), s2(j^2), s5(j^5), s7(j^7)} — matched to
    // DPP pair layout P0=(h,s1) P1=(s2,s3) P2=(s4,s5) P3=(s7,s6).
    const int a0 = j ^ 0, a1 = j ^ 3, a2 = j ^ 4, a3 = j ^ 6;
    const int c0 = j ^ 1, c1 = j ^ 2, c2 = j ^ 5, c3 = j ^ 7;
    v2f whA0 = v2f{sA * W_hh[r0 * 8 + a0], nL * W_hh[r1 * 8 + a0]};
    v2f whA1 = v2f{sA * W_hh[r0 * 8 + a1], nL * W_hh[r1 * 8 + a1]};
    v2f whA2 = v2f{sA * W_hh[r0 * 8 + a2], nL * W_hh[r1 * 8 + a2]};
    v2f whA3 = v2f{sA * W_hh[r0 * 8 + a3], nL * W_hh[r1 * 8 + a3]};
    v2f whB0 = v2f{sA * W_hh[r0 * 8 + c0], nL * W_hh[r1 * 8 + c0]};
    v2f whB1 = v2f{sA * W_hh[r0 * 8 + c1], nL * W_hh[r1 * 8 + c1]};
    v2f whB2 = v2f{sA * W_hh[r0 * 8 + c2], nL * W_hh[r1 * 8 + c2]};
    v2f whB3 = v2f{sA * W_hh[r0 * 8 + c3], nL * W_hh[r1 * 8 + c3]};

    v2f biasP = v2f{sA * (b_ih[r0] + b_hh[r0]), nL * (b_ih[r1] + b_hh[r1])};

    // ---- x staging (R1-verified): 512 threads cover 1024 float4/chunk ----
    const int st  = tid & 31;              // step within chunk
    const int se0 = tid >> 5;              // first element staged [0,16)
    const float* gp0 = x + (size_t)(blockIdx.x * EPB + se0) * (T_STEPS * 4) + st * 4;
    const int wl0 = se0 * ROWF + st * 4;   // LDS float index; +16*ROWF for q=1

    v4f v0, v1;
    v0 = *(const v4f*)(gp0);
    v1 = *(const v4f*)(gp0 + 16 * 2048);
    *(v4f*)&ldsx[wl0 + 0 * 16 * ROWF] = v0;
    *(v4f*)&ldsx[wl0 + 1 * 16 * ROWF] = v1;
    v0 = *(const v4f*)(gp0 + CHUNK * 4);
    v1 = *(const v4f*)(gp0 + CHUNK * 4 + 16 * 2048);
    __syncthreads();

    v2f hv = v2f{0.0f, 0.0f};          // hv.x = h (carried); hv.y = s1 scratch
    float ct = 0.0f;                   // ct = -2log2e * c (pre-scaled cell)
    v2f pP;                            // pipelined x-projection (step t)

    for (int n = 0; n < NCHUNK; ++n) {
        // PIN weights in VGPRs (belt-and-braces; residency proven
        // non-critical in R4, kept because it is free)
        asm volatile("" : "+v"(wx0), "+v"(wx1), "+v"(wx2), "+v"(wx3),
                          "+v"(biasP));
        asm volatile("" : "+v"(whA0), "+v"(whA1), "+v"(whA2), "+v"(whA3),
                          "+v"(whB0), "+v"(whB1), "+v"(whB2), "+v"(whB3));

        // publish chunk n+1 (regs loaded one chunk ago — long since landed)
        const int wb = ((n + 1) & 1) * BUFF + wl0;
        *(v4f*)&ldsx[wb + 0 * 16 * ROWF] = v0;
        *(v4f*)&ldsx[wb + 1 * 16 * ROWF] = v1;
        // fetch chunk n+2 (wraps; junk on last iters, never consumed)
        const int t2 = ((n + 2) & (NCHUNK - 1)) * (CHUNK * 4);
        v0 = *(const v4f*)(gp0 + t2);
        v1 = *(const v4f*)(gp0 + t2 + 16 * 2048);

        const float* xr = &ldsx[(n & 1) * BUFF + e * ROWF];

        // seed the x-projection pipeline with step 0 of this chunk
        {
            const v4f xc = *(const v4f*)(xr);
            const v2f x01 = __builtin_shufflevector(xc, xc, 0, 1);
            const v2f x23 = __builtin_shufflevector(xc, xc, 2, 3);
            pP = pk_fma_lo(wx0, x01, biasP);
            pk_fma_hi_acc(pP, wx1, x01);
            pk_fma_lo_acc(pP, wx2, x23);
            pk_fma_hi_acc(pP, wx3, x23);
        }

        #pragma unroll
        for (int t = 0; t < CHUNK; ++t) {
            // x for step t+1 (wrapped at t=31: junk, reseeded at chunk top)
            const v4f xn = *(const v4f*)(xr + (((t + 1) & (CHUNK - 1)) * 4));

            // all-DPP h exchange (depth 2), pairs land directly in halves
            hv.y = dppf<0xB1>(hv.x);           // s1
            v2f P3; P3.x = dppf<0x141>(hv.x);  // s7
            v2f P1; P1.x = dppf<0x4E>(hv.x);   // s2
                    P1.y = dppf<0x1B>(hv.x);   // s3
                    P3.y = dppf<0xB1>(P3.x);   // s6
            v2f P2; P2.x = dppf<0x1B>(P3.x);   // s4
                    P2.y = dppf<0x4E>(P3.x);   // s5

            // ONE pair-chain per lane (rows r0,r1), A/B sub-chains
            v2f A = pk_fma_lo(whA0, hv, pP);    // h
            v2f Bc = pk_mul_hi(whB0, hv);       // s1
            pk_fma_lo_acc(Bc, whB1, P1);        // s2
            pk_fma_hi_acc(A,  whA1, P1);        // s3
            pk_fma_lo_acc(A,  whA2, P2);        // s4
            pk_fma_hi_acc(Bc, whB2, P2);        // s5
            pk_fma_hi_acc(A,  whA3, P3);        // s6
            pk_fma_lo_acc(Bc, whB3, P3);        // s7
            const v2f g = pk_add2(A, Bc);       // (g_r0, g_r1)

            // SIMT-wide gate exponentials: half0 -> (eI,eF), half1 -> (eG,eO)
            const float eA = __builtin_amdgcn_exp2f(g.x);
            const float eB = __builtin_amdgcn_exp2f(g.y);

            // NEXT step's x-projection — h-independent, fills trans window
            {
                const v2f x01 = __builtin_shufflevector(xn, xn, 0, 1);
                const v2f x23 = __builtin_shufflevector(xn, xn, 2, 3);
                v2f nP = pk_fma_lo(wx0, x01, biasP);
                pk_fma_hi_acc(nP, wx1, x01);
                pk_fma_lo_acc(nP, wx2, x23);
                pk_fma_hi_acc(nP, wx3, x23);
                pP = nP;
            }

            // exchange exponentials across halves (composed xor8 DPP)
            const float eA8 = dppf<0x140>(dppf<0x141>(eA));
            const float eB8 = dppf<0x140>(dppf<0x141>(eB));

            const float eGv = hGO ? eA  : eA8;
            const float eFv = hGO ? eB8 : eB;
            const float eOv = hGO ? eB  : eB8;

            // folded rcp (R2): PIG=(1+eA)(1+eA8) == (1+eI)(1+eG) both halves
            const float pFv = 1.0f + eFv;
            const float PIG = (1.0f + eA) * (1.0f + eA8);
            const float r   = __builtin_amdgcn_rcpf(PIG * pFv);
            const float n2b = fmaf(eGv, P2L, n2L) * pFv;  // -2log2e*(i*g)*den
            const float n1  = ct * PIG;
            ct = (n1 + n2b) * r;                          // scaled cell update
            const float eC = __builtin_amdgcn_exp2f(ct);
            const float RC = __builtin_amdgcn_rcpf((1.0f + eOv) * (1.0f + eC));
            hv.x = (1.0f - eC) * RC;                      // o * tanh(c)
        }
        __syncthreads();
    }

    // out = h . W_fc + b_fc, reduced over lanes 0..7 (half1 copy identical)
    float pr = hv.x * W_fc[j];
    pr += __shfl_xor(pr, 1);
    pr += __shfl_xor(pr, 2);
    pr += __shfl_xor(pr, 4);
    if (L == 0) out[blockIdx.x * EPB + e] = pr + b_fc[0];
}

extern "C" void kernel_launch(void* const* d_in, const int* in_sizes, int n_in,
                              void* d_out, int out_size, void* d_ws, size_t ws_size,
                              hipStream_t stream) {
    const float* x    = (const float*)d_in[0];
    const float* W_ih = (const float*)d_in[1];
    const float* W_hh = (const float*)d_in[2];
    const float* b_ih = (const float*)d_in[3];
    const float* b_hh = (const float*)d_in[4];
    const float* W_fc = (const float*)d_in[5];
    const float* b_fc = (const float*)d_in[6];
    float* out = (float*)d_out;

    const int B = in_sizes[0] / (T_STEPS * 4);   // 8192
    const int block = 512;                       // 16 lanes/elem x 32 elems
    const int grid = B / EPB;                    // 256 blocks -> 2 waves/SIMD
    lstm_kernel<<<grid, block, 0, stream>>>(x, W_ih, W_hh, b_ih, b_hh, W_fc, b_fc, out, B);
}

// Round 8
// 184.586 us; speedup vs baseline: 1.0346x; 1.0346x over previous
//
#include <hip/hip_runtime.h>

#define T_STEPS 512
#define CHUNK   32
#define NCHUNK  (T_STEPS / CHUNK)   // 16
#define EPB     32                  // elements per 512-thread block (16 lanes/elem)
#define ROWF    132                 // padded row: 33 float4
#define BUFF    (EPB * ROWF)        // 4224 floats per buffer
#define LOG2E   1.4426950408889634f

typedef float v2f __attribute__((ext_vector_type(2)));
typedef float v4f __attribute__((ext_vector_type(4)));

// Packed fp32 ops with op_sel broadcasts (numerics verified R2/R4):
// _lo: both result halves read src1.LOW  (op_sel_hi:[1,0,1])
// _hi: both result halves read src1.HIGH (op_sel:[0,1,0] op_sel_hi:[1,1,1])
__device__ __forceinline__ v2f pk_fma_lo(v2f w, v2f s, v2f c) {
    v2f d;
    asm("v_pk_fma_f32 %0, %1, %2, %3 op_sel_hi:[1,0,1]"
        : "=v"(d) : "v"(w), "v"(s), "v"(c));
    return d;
}
__device__ __forceinline__ void pk_fma_lo_acc(v2f& a, v2f w, v2f s) {
    asm("v_pk_fma_f32 %0, %1, %2, %0 op_sel_hi:[1,0,1]"
        : "+v"(a) : "v"(w), "v"(s));
}
__device__ __forceinline__ void pk_fma_hi_acc(v2f& a, v2f w, v2f s) {
    asm("v_pk_fma_f32 %0, %1, %2, %0 op_sel:[0,1,0] op_sel_hi:[1,1,1]"
        : "+v"(a) : "v"(w), "v"(s));
}
__device__ __forceinline__ v2f pk_mul_hi(v2f w, v2f s) {
    v2f d;
    asm("v_pk_mul_f32 %0, %1, %2 op_sel:[0,1] op_sel_hi:[1,1]"
        : "=v"(d) : "v"(w), "v"(s));
    return d;
}
__device__ __forceinline__ v2f pk_add2(v2f a, v2f b) {
    v2f d;
    asm("v_pk_add_f32 %0, %1, %2" : "=v"(d) : "v"(a), "v"(b));
    return d;
}

// DPP cross-lane — BLOAT FIX (R8): mov_dpp has no tied old operand, so no
// per-DPP zero-materialization mov (update_dpp(0,..) forced one; 11/step).
// ctrls: xor1=0xB1, xor2=0x4E, xor3=0x1B (quad_perm);
// xor7(within 8)=row_half_mirror 0x141;
// xor8(within 16)=ROW_ROR:8 = 0x128 — single DPP (L -> (L+8)%16 == L^8),
// replaces the old 0x140 o 0x141 two-DPP composition.
template <int CTRL>
__device__ __forceinline__ float dppf(float v) {
#if __has_builtin(__builtin_amdgcn_mov_dpp)
    return __int_as_float(__builtin_amdgcn_mov_dpp(
        __float_as_int(v), CTRL, 0xF, 0xF, true));
#else
    return __int_as_float(__builtin_amdgcn_update_dpp(
        __float_as_int(v), __float_as_int(v), CTRL, 0xF, 0xF, true));
#endif
}

// 16 lanes/elem -> 2048 waves -> 2 waves/SIMD. R7 measured: occupancy 22,
// VALUBusy 75% -> ISSUE-BOUND at ~205 cyc/wave/step vs ~122 clean hand
// count. R8 = de-bloat: mov_dpp (no zero-movs), ror8 single-DPP xor8,
// in-place x-projection pipeline. Structure otherwise identical to R7
// (ran at 116.5 us, absmax 0).
__global__ __launch_bounds__(512, 2)
void lstm_kernel(
    const float* __restrict__ x, const float* __restrict__ W_ih,
    const float* __restrict__ W_hh, const float* __restrict__ b_ih,
    const float* __restrict__ b_hh, const float* __restrict__ W_fc,
    const float* __restrict__ b_fc, float* __restrict__ out, int B)
{
    __shared__ float ldsx[2 * BUFF];

    const int tid = threadIdx.x;
    const int e   = tid >> 4;          // block-local element [0,32)
    const int L   = tid & 15;          // lane within element
    const int j   = L & 7;             // hidden unit
    const bool hGO = (L & 8) != 0;     // false: (i,f) rows; true: (g,o) rows

    const float nL  = -LOG2E;          // scale for i,f,o rows
    const float n2L = -2.0f * LOG2E;   // scale for g row
    const float P2L =  2.0f * LOG2E;

    // ---- this lane's two gate rows, packed (r0,r1); scales pre-folded ----
    const int r0 = hGO ? 16 + j : j;        // g : i
    const int r1 = hGO ? 24 + j : 8 + j;    // o : f
    const float sA = hGO ? n2L : nL;        // r0 scale (g gets -2log2e)

    v2f wx0 = v2f{sA * W_ih[r0 * 4 + 0], nL * W_ih[r1 * 4 + 0]};
    v2f wx1 = v2f{sA * W_ih[r0 * 4 + 1], nL * W_ih[r1 * 4 + 1]};
    v2f wx2 = v2f{sA * W_ih[r0 * 4 + 2], nL * W_ih[r1 * 4 + 2]};
    v2f wx3 = v2f{sA * W_ih[r0 * 4 + 3], nL * W_ih[r1 * 4 + 3]};

    // chain A consumes {h(j^0), s3(j^3), s4(j^4), s6(j^6)},
    // chain B consumes {s1(j^1), s2(j^2), s5(j^5), s7(j^7)} — matched to
    // DPP pair layout P0=(h,s1) P1=(s2,s3) P2=(s4,s5) P3=(s7,s6).
    const int a0 = j ^ 0, a1 = j ^ 3, a2 = j ^ 4, a3 = j ^ 6;
    const int c0 = j ^ 1, c1 = j ^ 2, c2 = j ^ 5, c3 = j ^ 7;
    v2f whA0 = v2f{sA * W_hh[r0 * 8 + a0], nL * W_hh[r1 * 8 + a0]};
    v2f whA1 = v2f{sA * W_hh[r0 * 8 + a1], nL * W_hh[r1 * 8 + a1]};
    v2f whA2 = v2f{sA * W_hh[r0 * 8 + a2], nL * W_hh[r1 * 8 + a2]};
    v2f whA3 = v2f{sA * W_hh[r0 * 8 + a3], nL * W_hh[r1 * 8 + a3]};
    v2f whB0 = v2f{sA * W_hh[r0 * 8 + c0], nL * W_hh[r1 * 8 + c0]};
    v2f whB1 = v2f{sA * W_hh[r0 * 8 + c1], nL * W_hh[r1 * 8 + c1]};
    v2f whB2 = v2f{sA * W_hh[r0 * 8 + c2], nL * W_hh[r1 * 8 + c2]};
    v2f whB3 = v2f{sA * W_hh[r0 * 8 + c3], nL * W_hh[r1 * 8 + c3]};

    v2f biasP = v2f{sA * (b_ih[r0] + b_hh[r0]), nL * (b_ih[r1] + b_hh[r1])};

    // ---- x staging (R1-verified): 512 threads cover 1024 float4/chunk ----
    const int st  = tid & 31;              // step within chunk
    const int se0 = tid >> 5;              // first element staged [0,16)
    const float* gp0 = x + (size_t)(blockIdx.x * EPB + se0) * (T_STEPS * 4) + st * 4;
    const int wl0 = se0 * ROWF + st * 4;   // LDS float index; +16*ROWF for q=1

    v4f v0, v1;
    v0 = *(const v4f*)(gp0);
    v1 = *(const v4f*)(gp0 + 16 * 2048);
    *(v4f*)&ldsx[wl0 + 0 * 16 * ROWF] = v0;
    *(v4f*)&ldsx[wl0 + 1 * 16 * ROWF] = v1;
    v0 = *(const v4f*)(gp0 + CHUNK * 4);
    v1 = *(const v4f*)(gp0 + CHUNK * 4 + 16 * 2048);
    __syncthreads();

    v2f hv = v2f{0.0f, 0.0f};          // hv.x = h (carried); hv.y = s1 scratch
    float ct = 0.0f;                   // ct = -2log2e * c (pre-scaled cell)
    v2f pP;                            // pipelined x-projection (step t)

    for (int n = 0; n < NCHUNK; ++n) {
        // PIN weights in VGPRs (free insurance against remat-reload bloat)
        asm volatile("" : "+v"(wx0), "+v"(wx1), "+v"(wx2), "+v"(wx3),
                          "+v"(biasP));
        asm volatile("" : "+v"(whA0), "+v"(whA1), "+v"(whA2), "+v"(whA3),
                          "+v"(whB0), "+v"(whB1), "+v"(whB2), "+v"(whB3));

        // publish chunk n+1 (regs loaded one chunk ago — long since landed)
        const int wb = ((n + 1) & 1) * BUFF + wl0;
        *(v4f*)&ldsx[wb + 0 * 16 * ROWF] = v0;
        *(v4f*)&ldsx[wb + 1 * 16 * ROWF] = v1;
        // fetch chunk n+2 (wraps; junk on last iters, never consumed)
        const int t2 = ((n + 2) & (NCHUNK - 1)) * (CHUNK * 4);
        v0 = *(const v4f*)(gp0 + t2);
        v1 = *(const v4f*)(gp0 + t2 + 16 * 2048);

        const float* xr = &ldsx[(n & 1) * BUFF + e * ROWF];

        // seed the x-projection pipeline with step 0 of this chunk
        {
            const v4f xc = *(const v4f*)(xr);
            const v2f x01 = __builtin_shufflevector(xc, xc, 0, 1);
            const v2f x23 = __builtin_shufflevector(xc, xc, 2, 3);
            pP = pk_fma_lo(wx0, x01, biasP);
            pk_fma_hi_acc(pP, wx1, x01);
            pk_fma_lo_acc(pP, wx2, x23);
            pk_fma_hi_acc(pP, wx3, x23);
        }

        #pragma unroll
        for (int t = 0; t < CHUNK; ++t) {
            // x for step t+1 (wrapped at t=31: junk, reseeded at chunk top)
            const v4f xn = *(const v4f*)(xr + (((t + 1) & (CHUNK - 1)) * 4));

            // all-DPP h exchange (depth 2), pairs land directly in halves
            hv.y = dppf<0xB1>(hv.x);           // s1
            v2f P3; P3.x = dppf<0x141>(hv.x);  // s7
            v2f P1; P1.x = dppf<0x4E>(hv.x);   // s2
                    P1.y = dppf<0x1B>(hv.x);   // s3
                    P3.y = dppf<0xB1>(P3.x);   // s6
            v2f P2; P2.x = dppf<0x1B>(P3.x);   // s4
                    P2.y = dppf<0x4E>(P3.x);   // s5

            // ONE pair-chain per lane (rows r0,r1), A/B sub-chains
            v2f A = pk_fma_lo(whA0, hv, pP);    // h
            v2f Bc = pk_mul_hi(whB0, hv);       // s1
            pk_fma_lo_acc(Bc, whB1, P1);        // s2
            pk_fma_hi_acc(A,  whA1, P1);        // s3
            pk_fma_lo_acc(A,  whA2, P2);        // s4
            pk_fma_hi_acc(Bc, whB2, P2);        // s5
            pk_fma_hi_acc(A,  whA3, P3);        // s6
            pk_fma_lo_acc(Bc, whB3, P3);        // s7
            const v2f g = pk_add2(A, Bc);       // (g_r0, g_r1)

            // SIMT-wide gate exponentials: half0 -> (eI,eF), half1 -> (eG,eO)
            const float eA = __builtin_amdgcn_exp2f(g.x);
            const float eB = __builtin_amdgcn_exp2f(g.y);
            // exchange across halves: single-DPP xor8 (row_ror:8)
            const float eA8 = dppf<0x128>(eA);
            const float eB8 = dppf<0x128>(eB);

            // NEXT step's x-projection — h-independent, fills trans window;
            // pP already consumed by chain A's seed -> write in place
            {
                const v2f x01 = __builtin_shufflevector(xn, xn, 0, 1);
                const v2f x23 = __builtin_shufflevector(xn, xn, 2, 3);
                pP = pk_fma_lo(wx0, x01, biasP);
                pk_fma_hi_acc(pP, wx1, x01);
                pk_fma_lo_acc(pP, wx2, x23);
                pk_fma_hi_acc(pP, wx3, x23);
            }

            const float eGv = hGO ? eA  : eA8;
            const float eFv = hGO ? eB8 : eB;
            const float eOv = hGO ? eB  : eB8;

            // folded rcp (R2): PIG=(1+eA)(1+eA8) == (1+eI)(1+eG) both halves
            const float pFv = 1.0f + eFv;
            const float PIG = (1.0f + eA) * (1.0f + eA8);
            const float r   = __builtin_amdgcn_rcpf(PIG * pFv);
            const float n2b = fmaf(eGv, P2L, n2L) * pFv;  // -2log2e*(i*g)*den
            const float n1  = ct * PIG;
            ct = (n1 + n2b) * r;                          // scaled cell update
            const float eC = __builtin_amdgcn_exp2f(ct);
            const float RC = __builtin_amdgcn_rcpf((1.0f + eOv) * (1.0f + eC));
            hv.x = (1.0f - eC) * RC;                      // o * tanh(c)
        }
        __syncthreads();
    }

    // out = h . W_fc + b_fc, reduced over lanes 0..7 (half1 copy identical)
    float pr = hv.x * W_fc[j];
    pr += __shfl_xor(pr, 1);
    pr += __shfl_xor(pr, 2);
    pr += __shfl_xor(pr, 4);
    if (L == 0) out[blockIdx.x * EPB + e] = pr + b_fc[0];
}

extern "C" void kernel_launch(void* const* d_in, const int* in_sizes, int n_in,
                              void* d_out, int out_size, void* d_ws, size_t ws_size,
                              hipStream_t stream) {
    const float* x    = (const float*)d_in[0];
    const float* W_ih = (const float*)d_in[1];
    const float* W_hh = (const float*)d_in[2];
    const float* b_ih = (const float*)d_in[3];
    const float* b_hh = (const float*)d_in[4];
    const float* W_fc = (const float*)d_in[5];
    const float* b_fc = (const float*)d_in[6];
    float* out = (float*)d_out;

    const int B = in_sizes[0] / (T_STEPS * 4);   // 8192
    const int block = 512;                       // 16 lanes/elem x 32 elems
    const int grid = B / EPB;                    // 256 blocks -> 2 waves/SIMD
    lstm_kernel<<<grid, block, 0, stream>>>(x, W_ih, W_hh, b_ih, b_hh, W_fc, b_fc, out, B);
}

// Round 9
// 159.861 us; speedup vs baseline: 1.1946x; 1.1547x over previous
//
#include <hip/hip_runtime.h>

#define T_STEPS 512
#define CHUNK   32
#define NCHUNK  (T_STEPS / CHUNK)   // 16
#define EPB     32                  // elements per 256-thread block (8 lanes/elem)
#define ROWF    132                 // padded row: 33 float4
#define BUFF    (EPB * ROWF)        // 4224 floats per buffer
#define LOG2E   1.4426950408889634f

typedef float v2f __attribute__((ext_vector_type(2)));
typedef float v4f __attribute__((ext_vector_type(4)));

// Packed fp32 ops with op_sel broadcasts (numerics verified R2/R4):
// _lo: both result halves read src1.LOW  (op_sel_hi:[1,0,1])
// _hi: both result halves read src1.HIGH (op_sel:[0,1,0] op_sel_hi:[1,1,1])
__device__ __forceinline__ v2f pk_fma_lo(v2f w, v2f s, v2f c) {
    v2f d;
    asm("v_pk_fma_f32 %0, %1, %2, %3 op_sel_hi:[1,0,1]"
        : "=v"(d) : "v"(w), "v"(s), "v"(c));
    return d;
}
__device__ __forceinline__ void pk_fma_lo_acc(v2f& a, v2f w, v2f s) {
    asm("v_pk_fma_f32 %0, %1, %2, %0 op_sel_hi:[1,0,1]"
        : "+v"(a) : "v"(w), "v"(s));
}
__device__ __forceinline__ void pk_fma_hi_acc(v2f& a, v2f w, v2f s) {
    asm("v_pk_fma_f32 %0, %1, %2, %0 op_sel:[0,1,0] op_sel_hi:[1,1,1]"
        : "+v"(a) : "v"(w), "v"(s));
}
__device__ __forceinline__ v2f pk_mul_hi(v2f w, v2f s) {
    v2f d;
    asm("v_pk_mul_f32 %0, %1, %2 op_sel:[0,1] op_sel_hi:[1,1]"
        : "=v"(d) : "v"(w), "v"(s));
    return d;
}
__device__ __forceinline__ v2f pk_add2(v2f a, v2f b) {
    v2f d;
    asm("v_pk_add_f32 %0, %1, %2" : "=v"(d) : "v"(a), "v"(b));
    return d;
}

// Cross-lane xor within the 8-lane group — ALL DPP (mov_dpp: no tied old):
//  xor1=quad_perm 0xB1, xor2=0x4E, xor3=0x1B, xor7=row_half_mirror 0x141;
//  xor4/5/6 composed from s7: s4=qp<0x1B>(s7), s5=qp<0x4E>(s7), s6=qp<0xB1>(s7).
template <int CTRL>
__device__ __forceinline__ float dppf(float v) {
#if __has_builtin(__builtin_amdgcn_mov_dpp)
    return __int_as_float(__builtin_amdgcn_mov_dpp(
        __float_as_int(v), CTRL, 0xF, 0xF, true));
#else
    return __int_as_float(__builtin_amdgcn_update_dpp(
        __float_as_int(v), __float_as_int(v), CTRL, 0xF, 0xF, true));
#endif
}

// R9 = R4 chassis (best verified: 85.0 us, absmax 0) + depth-3 x-prefetch.
// Model (fitted over R0/R1/R4/R8): trans ops cost ~20 issue cyc at wave64;
// R4 issue = ~110 VALU + 7x~19 trans = 250 cyc/step (at its packing floor),
// stall = ~150, of which ~60-90 is exposed LDS latency (ds_read consumed
// ~40-60 cyc after issue vs ~120 cyc latency). This round: every ds_read
// issued 2 full steps (~800 cyc) before use — numerics untouched.
__global__ __launch_bounds__(256)
__attribute__((amdgpu_waves_per_eu(1, 1)))
void lstm_kernel(
    const float* __restrict__ x, const float* __restrict__ W_ih,
    const float* __restrict__ W_hh, const float* __restrict__ b_ih,
    const float* __restrict__ b_hh, const float* __restrict__ W_fc,
    const float* __restrict__ b_fc, float* __restrict__ out, int B)
{
    __shared__ float ldsx[2 * BUFF];

    const int tid = threadIdx.x;
    const int e   = tid >> 3;          // block-local element [0,32)
    const int j   = tid & 7;           // hidden unit

    const float nL  = -LOG2E;          // scale for i,f,o rows
    const float n2L = -2.0f * LOG2E;   // scale for g row
    const float P2L =  2.0f * LOG2E;

    const int ri = j, rf = 8 + j, rg = 16 + j, ro = 24 + j;

    // ---- loop-invariant weights, packed (i,f)/(g,o), scales pre-folded ----
    v2f wxIF0 = v2f{nL  * W_ih[ri * 4 + 0], nL * W_ih[rf * 4 + 0]};
    v2f wxIF1 = v2f{nL  * W_ih[ri * 4 + 1], nL * W_ih[rf * 4 + 1]};
    v2f wxIF2 = v2f{nL  * W_ih[ri * 4 + 2], nL * W_ih[rf * 4 + 2]};
    v2f wxIF3 = v2f{nL  * W_ih[ri * 4 + 3], nL * W_ih[rf * 4 + 3]};
    v2f wxGO0 = v2f{n2L * W_ih[rg * 4 + 0], nL * W_ih[ro * 4 + 0]};
    v2f wxGO1 = v2f{n2L * W_ih[rg * 4 + 1], nL * W_ih[ro * 4 + 1]};
    v2f wxGO2 = v2f{n2L * W_ih[rg * 4 + 2], nL * W_ih[ro * 4 + 2]};
    v2f wxGO3 = v2f{n2L * W_ih[rg * 4 + 3], nL * W_ih[ro * 4 + 3]};

    // chain A consumes {h(j^0), s3(j^3), s4(j^4), s6(j^6)},
    // chain B consumes {s1(j^1), s2(j^2), s5(j^5), s7(j^7)} — matched to
    // DPP pair layout P0=(h,s1) P1=(s2,s3) P2=(s4,s5) P3=(s7,s6).
    const int a0 = j ^ 0, a1 = j ^ 3, a2 = j ^ 4, a3 = j ^ 6;
    const int c0 = j ^ 1, c1 = j ^ 2, c2 = j ^ 5, c3 = j ^ 7;
    v2f whA0IF = v2f{nL * W_hh[ri * 8 + a0], nL * W_hh[rf * 8 + a0]};
    v2f whA1IF = v2f{nL * W_hh[ri * 8 + a1], nL * W_hh[rf * 8 + a1]};
    v2f whA2IF = v2f{nL * W_hh[ri * 8 + a2], nL * W_hh[rf * 8 + a2]};
    v2f whA3IF = v2f{nL * W_hh[ri * 8 + a3], nL * W_hh[rf * 8 + a3]};
    v2f whB0IF = v2f{nL * W_hh[ri * 8 + c0], nL * W_hh[rf * 8 + c0]};
    v2f whB1IF = v2f{nL * W_hh[ri * 8 + c1], nL * W_hh[rf * 8 + c1]};
    v2f whB2IF = v2f{nL * W_hh[ri * 8 + c2], nL * W_hh[rf * 8 + c2]};
    v2f whB3IF = v2f{nL * W_hh[ri * 8 + c3], nL * W_hh[rf * 8 + c3]};
    v2f whA0GO = v2f{n2L * W_hh[rg * 8 + a0], nL * W_hh[ro * 8 + a0]};
    v2f whA1GO = v2f{n2L * W_hh[rg * 8 + a1], nL * W_hh[ro * 8 + a1]};
    v2f whA2GO = v2f{n2L * W_hh[rg * 8 + a2], nL * W_hh[ro * 8 + a2]};
    v2f whA3GO = v2f{n2L * W_hh[rg * 8 + a3], nL * W_hh[ro * 8 + a3]};
    v2f whB0GO = v2f{n2L * W_hh[rg * 8 + c0], nL * W_hh[ro * 8 + c0]};
    v2f whB1GO = v2f{n2L * W_hh[rg * 8 + c1], nL * W_hh[ro * 8 + c1]};
    v2f whB2GO = v2f{n2L * W_hh[rg * 8 + c2], nL * W_hh[ro * 8 + c2]};
    v2f whB3GO = v2f{n2L * W_hh[rg * 8 + c3], nL * W_hh[ro * 8 + c3]};

    v2f biasIF = v2f{nL  * (b_ih[ri] + b_hh[ri]), nL * (b_ih[rf] + b_hh[rf])};
    v2f biasGO = v2f{n2L * (b_ih[rg] + b_hh[rg]), nL * (b_ih[ro] + b_hh[ro])};

    // ---- x staging: thread covers flat slots tid + q*256 ----
    const int st  = tid & 31;              // step within chunk
    const int se0 = tid >> 5;              // first element this thread stages
    const float* gp0 = x + (size_t)(blockIdx.x * EPB + se0) * (T_STEPS * 4) + st * 4;
    const int wl0 = se0 * ROWF + st * 4;   // LDS float index, +q*8*ROWF per q

    v4f v0, v1, v2, v3;
    v0 = *(const v4f*)(gp0);
    v1 = *(const v4f*)(gp0 + 8 * 2048);
    v2 = *(const v4f*)(gp0 + 16 * 2048);
    v3 = *(const v4f*)(gp0 + 24 * 2048);
    *(v4f*)&ldsx[wl0 + 0 * 8 * ROWF] = v0;
    *(v4f*)&ldsx[wl0 + 1 * 8 * ROWF] = v1;
    *(v4f*)&ldsx[wl0 + 2 * 8 * ROWF] = v2;
    *(v4f*)&ldsx[wl0 + 3 * 8 * ROWF] = v3;
    v0 = *(const v4f*)(gp0 + CHUNK * 4);
    v1 = *(const v4f*)(gp0 + CHUNK * 4 + 8 * 2048);
    v2 = *(const v4f*)(gp0 + CHUNK * 4 + 16 * 2048);
    v3 = *(const v4f*)(gp0 + CHUNK * 4 + 24 * 2048);
    __syncthreads();

    v2f hv = v2f{0.0f, 0.0f};          // hv.x = h (carried); hv.y = s1 scratch
    float ct = 0.0f;                   // ct = -2log2e * c (pre-scaled cell)
    v2f pIF, pGO;                      // pipelined x-projection (step t)

    for (int n = 0; n < NCHUNK; ++n) {
        // PIN the weight set in VGPRs (free; prevents remat-reload churn)
        asm volatile("" : "+v"(wxIF0), "+v"(wxIF1), "+v"(wxIF2), "+v"(wxIF3),
                          "+v"(wxGO0), "+v"(wxGO1), "+v"(wxGO2), "+v"(wxGO3),
                          "+v"(biasIF), "+v"(biasGO));
        asm volatile("" : "+v"(whA0IF), "+v"(whA1IF), "+v"(whA2IF), "+v"(whA3IF),
                          "+v"(whA0GO), "+v"(whA1GO), "+v"(whA2GO), "+v"(whA3GO));
        asm volatile("" : "+v"(whB0IF), "+v"(whB1IF), "+v"(whB2IF), "+v"(whB3IF),
                          "+v"(whB0GO), "+v"(whB1GO), "+v"(whB2GO), "+v"(whB3GO));

        // publish chunk n+1 (regs loaded one chunk ago — long since landed)
        const int wb = ((n + 1) & 1) * BUFF + wl0;
        *(v4f*)&ldsx[wb + 0 * 8 * ROWF] = v0;
        *(v4f*)&ldsx[wb + 1 * 8 * ROWF] = v1;
        *(v4f*)&ldsx[wb + 2 * 8 * ROWF] = v2;
        *(v4f*)&ldsx[wb + 3 * 8 * ROWF] = v3;
        // fetch chunk n+2 (wraps; junk on last iters, never consumed)
        const int t2 = ((n + 2) & (NCHUNK - 1)) * (CHUNK * 4);
        v0 = *(const v4f*)(gp0 + t2);
        v1 = *(const v4f*)(gp0 + t2 + 8 * 2048);
        v2 = *(const v4f*)(gp0 + t2 + 16 * 2048);
        v3 = *(const v4f*)(gp0 + t2 + 24 * 2048);

        const float* xr = &ldsx[(n & 1) * BUFF + e * ROWF];

        // chunk-top seeds (post-barrier): x[0] -> pP, x[1] -> xA, x[2] -> xB
        v4f xA, xB;
        {
            const v4f xc = *(const v4f*)(xr);
            xA = *(const v4f*)(xr + 4);
            xB = *(const v4f*)(xr + 8);
            const v2f x01 = __builtin_shufflevector(xc, xc, 0, 1);
            const v2f x23 = __builtin_shufflevector(xc, xc, 2, 3);
            pIF = pk_fma_lo(wxIF0, x01, biasIF);
            pGO = pk_fma_lo(wxGO0, x01, biasGO);
            pk_fma_hi_acc(pIF, wxIF1, x01);  pk_fma_hi_acc(pGO, wxGO1, x01);
            pk_fma_lo_acc(pIF, wxIF2, x23);  pk_fma_lo_acc(pGO, wxGO2, x23);
            pk_fma_hi_acc(pIF, wxIF3, x23);  pk_fma_hi_acc(pGO, wxGO3, x23);
        }

        #pragma unroll
        for (int t = 0; t < CHUNK; ++t) {
            // depth-3 prefetch: issue x[t+3] now (~2 steps before its use);
            // no load for t>=29 (x[31] already in flight from t=28)
            v4f xN;
            if (t < CHUNK - 3) xN = *(const v4f*)(xr + ((t + 3) * 4));

            // all-DPP h exchange (depth 2), pairs land directly in halves
            hv.y = dppf<0xB1>(hv.x);           // s1
            v2f P3; P3.x = dppf<0x141>(hv.x);  // s7
            v2f P1; P1.x = dppf<0x4E>(hv.x);   // s2
                    P1.y = dppf<0x1B>(hv.x);   // s3
                    P3.y = dppf<0xB1>(P3.x);   // s6
            v2f P2; P2.x = dppf<0x1B>(P3.x);   // s4
                    P2.y = dppf<0x4E>(P3.x);   // s5

            // gate chains seeded with the PIPELINED x-projection
            v2f A_IF = pk_fma_lo(whA0IF, hv, pIF);   // h
            v2f A_GO = pk_fma_lo(whA0GO, hv, pGO);
            v2f B_IF = pk_mul_hi(whB0IF, hv);         // s1
            v2f B_GO = pk_mul_hi(whB0GO, hv);
            pk_fma_lo_acc(B_IF, whB1IF, P1);  pk_fma_lo_acc(B_GO, whB1GO, P1); // s2
            pk_fma_hi_acc(A_IF, whA1IF, P1);  pk_fma_hi_acc(A_GO, whA1GO, P1); // s3
            pk_fma_lo_acc(A_IF, whA2IF, P2);  pk_fma_lo_acc(A_GO, whA2GO, P2); // s4
            pk_fma_hi_acc(B_IF, whB2IF, P2);  pk_fma_hi_acc(B_GO, whB2GO, P2); // s5
            pk_fma_hi_acc(A_IF, whA3IF, P3);  pk_fma_hi_acc(A_GO, whA3GO, P3); // s6
            pk_fma_lo_acc(B_IF, whB3IF, P3);  pk_fma_lo_acc(B_GO, whB3GO, P3); // s7
            const v2f gIF = pk_add2(A_IF, B_IF);  // (ãi, ãf)
            const v2f gGO = pk_add2(A_GO, B_GO);  // (ãg, ão)

            // gate exponentials — args pre-scaled
            const float eI = __builtin_amdgcn_exp2f(gIF.x);
            const float eF = __builtin_amdgcn_exp2f(gIF.y);
            const float eG = __builtin_amdgcn_exp2f(gGO.x);
            const float eO = __builtin_amdgcn_exp2f(gGO.y);

            // NEXT step's x-projection from xA (loaded 2 steps ago) —
            // h-independent, textually in the exp2 latency window
            {
                const v2f x01 = __builtin_shufflevector(xA, xA, 0, 1);
                const v2f x23 = __builtin_shufflevector(xA, xA, 2, 3);
                pIF = pk_fma_lo(wxIF0, x01, biasIF);
                pGO = pk_fma_lo(wxGO0, x01, biasGO);
                pk_fma_hi_acc(pIF, wxIF1, x01);  pk_fma_hi_acc(pGO, wxGO1, x01);
                pk_fma_lo_acc(pIF, wxIF2, x23);  pk_fma_lo_acc(pGO, wxGO2, x23);
                pk_fma_hi_acc(pIF, wxIF3, x23);  pk_fma_hi_acc(pGO, wxGO3, x23);
            }

            // folded rcp: ct' = (ct*PIG + (n2L - n2L*eG)*pF) / (PIG*pF)
            const float pFv = 1.0f + eF;
            const float PIG = (1.0f + eI) * (1.0f + eG);
            const float r   = __builtin_amdgcn_rcpf(PIG * pFv);
            const float n2b = fmaf(eG, P2L, n2L) * pFv;  // -2log2e*(i*g)*den
            const float n1  = ct * PIG;
            ct = (n1 + n2b) * r;                         // scaled cell update
            const float eC = __builtin_amdgcn_exp2f(ct);
            const float RC = __builtin_amdgcn_rcpf((1.0f + eO) * (1.0f + eC));
            hv.x = (1.0f - eC) * RC;                     // o * tanh(c)

            // rotate the x pipeline (pure register renames after unroll)
            xA = xB;
            xB = xN;
        }
        __syncthreads();
    }

    // out = h . W_fc + b_fc, reduced over the 8-lane group
    float pr = hv.x * W_fc[j];
    pr += __shfl_xor(pr, 1);
    pr += __shfl_xor(pr, 2);
    pr += __shfl_xor(pr, 4);
    if (j == 0) out[blockIdx.x * EPB + e] = pr + b_fc[0];
}

extern "C" void kernel_launch(void* const* d_in, const int* in_sizes, int n_in,
                              void* d_out, int out_size, void* d_ws, size_t ws_size,
                              hipStream_t stream) {
    const float* x    = (const float*)d_in[0];
    const float* W_ih = (const float*)d_in[1];
    const float* W_hh = (const float*)d_in[2];
    const float* b_ih = (const float*)d_in[3];
    const float* b_hh = (const float*)d_in[4];
    const float* W_fc = (const float*)d_in[5];
    const float* b_fc = (const float*)d_in[6];
    float* out = (float*)d_out;

    const int B = in_sizes[0] / (T_STEPS * 4);   // 8192
    const int block = 256;
    const int grid = (B * 8) / block;            // 256 blocks = 1/CU
    lstm_kernel<<<grid, block, 0, stream>>>(x, W_ih, W_hh, b_ih, b_hh, W_fc, b_fc, out, B);
}